// Round 4
// baseline (313.192 us; speedup 1.0000x reference)
//
#include <hip/hip_runtime.h>
#include <math.h>

#define NUM_KV_HEADS 8
#define HEAD_DIM 128
#define HD (NUM_KV_HEADS * HEAD_DIM)    // 1024 floats = 4 KB row
#define BLOCK_SZ 16
#define MODEL_CTX 4096
#define TC 64                            // tokens per chunk (workgroup)
#define TJ 4                             // tokens per LDS tile
#define NT (TC / TJ)                     // 16 tiles
#define NEG_BIG (-1e30f)

typedef const __attribute__((address_space(1))) float* gptr_t;
typedef __attribute__((address_space(3))) float* lptr_t;

// Kernel 0: rope cos/sin table. float4 at (t*128 + 4*f2) = {cos(f0),sin(f0),cos(f1),sin(f1)}
// for f0=2*f2, f1=2*f2+1.
__global__ void rope_table(float* __restrict__ tab, int ntab) {
    const int idx = blockIdx.x * 256 + threadIdx.x;   // t*64 + f
    if (idx >= ntab * 64) return;
    const int t = idx >> 6;
    const int f = idx & 63;
    const float inv = expf(-9.210340371976184f * (float)f * (1.0f / 64.0f));
    float s, c;
    sincosf((float)t * inv, &s, &c);
    tab[2 * idx]     = c;
    tab[2 * idx + 1] = s;
}

// Kernel 1: workgroup = (b, 64-token chunk). Whole 4KB K/V rows staged to LDS
// via global_load_lds (no VGPR cost, deep queue), double-buffered 4-token tiles.
// Half-wave hw computes token hw%4, heads (hw/4)*4 .. +3, online softmax.
__global__ __launch_bounds__(256, 2)
void attn_partial(const float* __restrict__ q,
                  const float* __restrict__ knew,
                  const float* __restrict__ vnew,
                  const float* __restrict__ kcache,
                  const float* __restrict__ vcache,
                  const int* __restrict__ btab,
                  const int* __restrict__ seqlen_p,
                  const float* __restrict__ tab,
                  int nbps,
                  float* __restrict__ o_part,    // [B*H][n_chunks][128]
                  float* __restrict__ m_part,
                  float* __restrict__ l_part,
                  int n_chunks)
{
    const int chunk = blockIdx.x;
    const int b     = blockIdx.y;
    const int tid   = threadIdx.x;
    const int wave  = tid >> 6;
    const int lane  = tid & 63;
    const int sl    = lane & 31;
    const int half  = lane >> 5;
    const int hw    = wave * 2 + half;     // 0..7
    const int jslot = hw & 3;              // token slot this half-wave computes
    const int hbase = (hw >> 2) * 4;       // head group base (0 or 4)

    __shared__ union {
        float kv[2][TJ][2][HD];            // [buf][token][K/V][1024]  = 64 KB
        float po[8][4][HEAD_DIM];          // reuse for final combine  = 16 KB
    } smem;
    __shared__ float msc[8][4], lsc[8][4];

    const int seq_len = *seqlen_p;
    const int rem = (seq_len - 1) & (BLOCK_SZ - 1);
    const int T   = (nbps - 1) * BLOCK_SZ + rem + 1;
    const int Tm1 = T - 1;

    // this chunk's 4 cache-block ids (uniform scalar loads)
    int rows[TC / BLOCK_SZ];
    #pragma unroll
    for (int i = 0; i < TC / BLOCK_SZ; i++)
        rows[i] = btab[b * nbps + chunk * (TC / BLOCK_SZ) + i];

    const float* knb = knew + (size_t)b * HD;
    const float* vnb = vnew + (size_t)b * HD;
    const int t0c = chunk * TC;

    // roped q for this half-wave's 4 heads (pos MODEL_CTX-1)
    float qr[4][4];
    {
        const float4 qcs = *(const float4*)(tab + (size_t)(MODEL_CTX - 1) * 128 + 4 * sl);
        #pragma unroll
        for (int hh = 0; hh < 4; hh++) {
            const float* qb = q + (size_t)b * HD + (hbase + hh) * HEAD_DIM;
            const float2 q1 = *(const float2*)(qb + 2 * sl);
            const float2 q2 = *(const float2*)(qb + 64 + 2 * sl);
            qr[hh][0] = q1.x * qcs.x - q2.x * qcs.y;
            qr[hh][1] = q1.y * qcs.z - q2.y * qcs.w;
            qr[hh][2] = q2.x * qcs.x + q1.x * qcs.y;
            qr[hh][3] = q2.y * qcs.z + q1.y * qcs.w;
        }
    }

    float mh[4]  = {NEG_BIG, NEG_BIG, NEG_BIG, NEG_BIG};
    float lh[4]  = {0.f, 0.f, 0.f, 0.f};
    float acc[4][4] = {};

    const int loff = wave * 256 + (lane << 2);   // this lane's float offset in a row

    auto stage = [&](int buf, int ti) {
        #pragma unroll
        for (int j = 0; j < TJ; j++) {
            const int o = ti * TJ + j;
            const int t = t0c + o;
            const float* ks;
            const float* vs;
            if (t == Tm1) { ks = knb; vs = vnb; }
            else {
                const size_t row = (size_t)rows[o >> 4] * BLOCK_SZ + (o & 15);
                ks = kcache + row * HD;
                vs = vcache + row * HD;
            }
            __builtin_amdgcn_global_load_lds((gptr_t)(ks + loff),
                (lptr_t)&smem.kv[buf][j][0][wave * 256], 16, 0, 0);
            __builtin_amdgcn_global_load_lds((gptr_t)(vs + loff),
                (lptr_t)&smem.kv[buf][j][1][wave * 256], 16, 0, 0);
        }
    };

    auto compute = [&](int buf, int ti) {
        const int o  = ti * TJ + jslot;
        const int t  = t0c + o;
        const int tt = (t == Tm1) ? (MODEL_CTX - 1) : t;
        const float4 cs = *(const float4*)(tab + (size_t)tt * 128 + 4 * sl);
        const bool valid = (t < T);
        const float* kr = &smem.kv[buf][jslot][0][0];
        const float* vr = &smem.kv[buf][jslot][1][0];
        #pragma unroll
        for (int hh = 0; hh < 4; hh++) {
            const int ho = (hbase + hh) * HEAD_DIM;
            const float2 k1 = *(const float2*)(kr + ho + 2 * sl);
            const float2 k2 = *(const float2*)(kr + ho + 64 + 2 * sl);
            const float2 v1 = *(const float2*)(vr + ho + 2 * sl);
            const float2 v2 = *(const float2*)(vr + ho + 64 + 2 * sl);
            const float r0 = k1.x * cs.x - k2.x * cs.y;
            const float r1 = k1.y * cs.z - k2.y * cs.w;
            const float r2 = k2.x * cs.x + k1.x * cs.y;
            const float r3 = k2.y * cs.z + k1.y * cs.w;
            float d = r0 * qr[hh][0] + r1 * qr[hh][1] + r2 * qr[hh][2] + r3 * qr[hh][3];
            #pragma unroll
            for (int off = 1; off < 32; off <<= 1) d += __shfl_xor(d, off, 64);
            const float s  = valid ? d * 0.08838834764831845f : NEG_BIG;
            const float mn = fmaxf(mh[hh], s);
            const float al = __expf(mh[hh] - mn);
            const float p  = __expf(s - mn);
            lh[hh]     = lh[hh] * al + p;
            acc[hh][0] = acc[hh][0] * al + p * v1.x;
            acc[hh][1] = acc[hh][1] * al + p * v1.y;
            acc[hh][2] = acc[hh][2] * al + p * v2.x;
            acc[hh][3] = acc[hh][3] * al + p * v2.y;
            mh[hh] = mn;
        }
    };

    stage(0, 0);
    int buf = 0;
    for (int ti = 0; ti < NT; ti++) {
        __syncthreads();                       // waits ONLY the tile issued last iter
        if (ti + 1 < NT) stage(buf ^ 1, ti + 1);  // next tile flies during compute
        compute(buf, ti);
        buf ^= 1;
    }

    // ---- combine the 4 half-waves sharing each head ----
    __syncthreads();
    #pragma unroll
    for (int hh = 0; hh < 4; hh++) {
        float* p = &smem.po[hw][hh][0];
        p[2 * sl]      = acc[hh][0];
        p[2 * sl + 1]  = acc[hh][1];
        p[64 + 2 * sl] = acc[hh][2];
        p[65 + 2 * sl] = acc[hh][3];
    }
    if (sl == 0) {
        #pragma unroll
        for (int hh = 0; hh < 4; hh++) { msc[hw][hh] = mh[hh]; lsc[hw][hh] = lh[hh]; }
    }
    __syncthreads();

    const int h  = tid >> 5;          // 0..7
    const int s2 = tid & 31;
    const int g4 = (h >> 2) * 4;      // half-wave group base for this head
    const int hh = h & 3;
    float M = NEG_BIG;
    #pragma unroll
    for (int jj = 0; jj < 4; jj++) M = fmaxf(M, msc[g4 + jj][hh]);
    float L = 0.f, n0 = 0.f, n1 = 0.f, n2 = 0.f, n3 = 0.f;
    #pragma unroll
    for (int jj = 0; jj < 4; jj++) {
        const float w = __expf(msc[g4 + jj][hh] - M);
        L  += w * lsc[g4 + jj][hh];
        n0 += w * smem.po[g4 + jj][hh][2 * s2];
        n1 += w * smem.po[g4 + jj][hh][2 * s2 + 1];
        n2 += w * smem.po[g4 + jj][hh][64 + 2 * s2];
        n3 += w * smem.po[g4 + jj][hh][65 + 2 * s2];
    }
    const int bh = b * NUM_KV_HEADS + h;
    float* op = o_part + ((size_t)bh * n_chunks + chunk) * HEAD_DIM;
    op[2 * s2]      = n0;
    op[2 * s2 + 1]  = n1;
    op[64 + 2 * s2] = n2;
    op[65 + 2 * s2] = n3;
    if (s2 == 0) {
        m_part[bh * n_chunks + chunk] = M;
        l_part[bh * n_chunks + chunk] = L;
    }
}

// Kernel 2: combine split-K partials.
__global__ void attn_combine(const float* __restrict__ o_part,
                             const float* __restrict__ m_part,
                             const float* __restrict__ l_part,
                             float* __restrict__ out,
                             int n_chunks)
{
    const int bh = blockIdx.x;
    const int d  = threadIdx.x;

    float M = -INFINITY;
    for (int c = 0; c < n_chunks; c++) M = fmaxf(M, m_part[bh * n_chunks + c]);
    float L = 0.f, num = 0.f;
    for (int c = 0; c < n_chunks; c++) {
        const float w = __expf(m_part[bh * n_chunks + c] - M);
        L   += l_part[bh * n_chunks + c] * w;
        num += w * o_part[((size_t)bh * n_chunks + c) * HEAD_DIM + d];
    }
    out[(size_t)bh * HEAD_DIM + d] = num / L;
}

extern "C" void kernel_launch(void* const* d_in, const int* in_sizes, int n_in,
                              void* d_out, int out_size, void* d_ws, size_t ws_size,
                              hipStream_t stream) {
    const float* q  = (const float*)d_in[0];
    const float* k  = (const float*)d_in[1];
    const float* v  = (const float*)d_in[2];
    const float* kc = (const float*)d_in[3];
    const float* vc = (const float*)d_in[4];
    const int* bt   = (const int*)d_in[5];
    const int* slp  = (const int*)d_in[7];

    const int B    = in_sizes[0] / HD;
    const int nbps = in_sizes[5] / B;                     // 256
    const int n_chunks = (nbps * BLOCK_SZ) / TC;          // 64
    const int BH = B * NUM_KV_HEADS;

    int ntab = nbps * BLOCK_SZ;
    if (ntab < MODEL_CTX) ntab = MODEL_CTX;

    float* tab    = (float*)d_ws;                          // ntab*128 floats
    float* o_part = tab + (size_t)ntab * 128;
    float* m_part = o_part + (size_t)BH * n_chunks * HEAD_DIM;
    float* l_part = m_part + (size_t)BH * n_chunks;

    rope_table<<<(ntab * 64 + 255) / 256, 256, 0, stream>>>(tab, ntab);

    dim3 g1(n_chunks, B);
    attn_partial<<<g1, 256, 0, stream>>>(q, k, v, kc, vc, bt, slp, tab, nbps,
                                         o_part, m_part, l_part, n_chunks);
    attn_combine<<<dim3(BH), HEAD_DIM, 0, stream>>>(o_part, m_part, l_part,
                                                    (float*)d_out, n_chunks);
}